// Round 5
// baseline (4511.665 us; speedup 1.0000x reference)
//
#include <hip/hip_runtime.h>
#include <stdint.h>

// ---------------------------------------------------------------------------
// DecoderLSTM: B=32, S=128, H=1024, L=2, V=32000, teacher forcing (tf=1)
//
//   1. cvt weights/emb -> bf16, bsum = b_ih+b_hh, h/c inits.
//   2. embed tokens -> x_seq bf16 [4096][1024] (rows t*32+b)     (in d_out)
//   3. Zx0 = x_seq @ w_ih[0]^T + bsum0  (MFMA GEMM, f32)         (in d_out)
//   4. ONE persistent kernel, fence-free producer/consumer sync:
//        - all cross-WG h data: sc1 write-through stores + sc1 loads
//          (relaxed AGENT atomics) -> no buffer_wbl2 / buffer_inv ever.
//        - layer0 (64 WGs, 16 units) gated on arr0; layer1 (128 WGs,
//          8 units) gated on arr0 + arr1. Layer0 runs ahead (slack pipeline).
//   5. out = outb @ emb_bf^T (MFMA GEMM, M=4096, N=32000, K=1024)
// ---------------------------------------------------------------------------

typedef __attribute__((ext_vector_type(8))) short short8;
typedef __attribute__((ext_vector_type(4))) float f32x4;

#define MFMA16(a, b, c) __builtin_amdgcn_mfma_f32_16x16x32_bf16((a), (b), (c), 0, 0, 0)

__device__ __forceinline__ unsigned short f2bf(float f) {
  union { float f; unsigned int u; } v; v.f = f;
  unsigned int u = v.u;
  return (unsigned short)((u + 0x7fffu + ((u >> 16) & 1u)) >> 16);
}

// device-coherent (sc1) primitives: relaxed AGENT atomics. Stores write
// through the XCD L2 (ACK at coherence point => per-wave vmcnt(0) drain at
// __syncthreads orders them before the subsequent counter add). Loads bypass
// the possibly-stale local L2 and read the coherence point (L3).
__device__ __forceinline__ void st_u32_dev(unsigned* p, unsigned v) {
  __hip_atomic_store(p, v, __ATOMIC_RELAXED, __HIP_MEMORY_SCOPE_AGENT);
}
__device__ __forceinline__ short8 ld16_dev(const unsigned short* p) {
  union { unsigned long long q[2]; short8 v; } r;
  const unsigned long long* pp = (const unsigned long long*)p;
  r.q[0] = __hip_atomic_load(pp, __ATOMIC_RELAXED, __HIP_MEMORY_SCOPE_AGENT);
  r.q[1] = __hip_atomic_load(pp + 1, __ATOMIC_RELAXED, __HIP_MEMORY_SCOPE_AGENT);
  return r.v;
}
__device__ __forceinline__ void poll_ge(unsigned* c, unsigned tgt) {
  while (__hip_atomic_load(c, __ATOMIC_RELAXED, __HIP_MEMORY_SCOPE_AGENT) < tgt)
    __builtin_amdgcn_s_sleep(1);
}
__device__ __forceinline__ void arrive(unsigned* c) {
  __hip_atomic_fetch_add(c, 1u, __ATOMIC_RELAXED, __HIP_MEMORY_SCOPE_AGENT);
}

// ---- conversion / small kernels -------------------------------------------

__global__ void cvt_bf16_k(const float* __restrict__ s, unsigned short* __restrict__ d, int n4) {
  int i = blockIdx.x * blockDim.x + threadIdx.x;
  int st = gridDim.x * blockDim.x;
  for (; i < n4; i += st) {
    float4 v = ((const float4*)s)[i];
    ushort4 o;
    o.x = f2bf(v.x); o.y = f2bf(v.y); o.z = f2bf(v.z); o.w = f2bf(v.w);
    ((ushort4*)d)[i] = o;
  }
}

__global__ void bias_sum_k(const float* __restrict__ a, const float* __restrict__ b,
                           float* __restrict__ o, int n) {
  int i = blockIdx.x * blockDim.x + threadIdx.x;
  if (i < n) o[i] = a[i] + b[i];
}

__global__ void embed_k(const int* __restrict__ x, const int* __restrict__ tgt,
                        const float* __restrict__ emb, unsigned short* __restrict__ xseq) {
  int row = blockIdx.x;          // t*32 + b
  int t = row >> 5, b = row & 31;
  int tok = (t == 0) ? x[b] : tgt[b * 128 + t];
  const float4* e = (const float4*)(emb + (size_t)tok * 1024);
  ushort4* o = (ushort4*)(xseq + (size_t)row * 1024);
  int i = threadIdx.x;
  float4 v = e[i];
  ushort4 u;
  u.x = f2bf(v.x); u.y = f2bf(v.y); u.z = f2bf(v.z); u.w = f2bf(v.w);
  o[i] = u;
}

// ---- bf16 MFMA GEMM: C[M][N] = A[M][K] * B[N][K]^T (+bias[col]) -----------
// (verified in round 1; unchanged this round)

__global__ __launch_bounds__(256, 2) void gemm_bf16_k(
    const unsigned short* __restrict__ A, const unsigned short* __restrict__ B,
    float* __restrict__ C, const float* __restrict__ bias, int N) {
  __shared__ __align__(16) unsigned short As[128 * 64];
  __shared__ __align__(16) unsigned short Bs[128 * 64];
  const int tid = threadIdx.x;
  const int lane = tid & 63;
  const int w = tid >> 6;
  const int wm = w >> 1, wn = w & 1;
  const int mBase = blockIdx.y * 128;
  const int nBase = blockIdx.x * 128;
  const int lr = lane & 15, lk = lane >> 4;
  const int K = 1024;

  f32x4 acc[4][4];
#pragma unroll
  for (int i = 0; i < 4; ++i)
#pragma unroll
    for (int j = 0; j < 4; ++j) acc[i][j] = (f32x4){0.f, 0.f, 0.f, 0.f};

  for (int kt = 0; kt < K / 64; ++kt) {
    int4 va[4], vb[4];
#pragma unroll
    for (int r = 0; r < 4; ++r) {
      int q = r * 256 + tid;
      int row = q >> 3, c = q & 7;
      va[r] = *(const int4*)(A + (size_t)(mBase + row) * K + kt * 64 + c * 8);
      vb[r] = *(const int4*)(B + (size_t)(nBase + row) * K + kt * 64 + c * 8);
    }
    __syncthreads();
#pragma unroll
    for (int r = 0; r < 4; ++r) {
      int q = r * 256 + tid;
      int row = q >> 3, c = q & 7;
      int cs = c ^ (row & 7);
      *(int4*)&As[row * 64 + cs * 8] = va[r];
      *(int4*)&Bs[row * 64 + cs * 8] = vb[r];
    }
    __syncthreads();
#pragma unroll
    for (int ks = 0; ks < 2; ++ks) {
      short8 a[4], b[4];
#pragma unroll
      for (int mf = 0; mf < 4; ++mf) {
        int row = wm * 64 + mf * 16 + lr;
        int cc = (ks * 4 + lk) ^ (row & 7);
        a[mf] = *(const short8*)&As[row * 64 + cc * 8];
      }
#pragma unroll
      for (int nf = 0; nf < 4; ++nf) {
        int row = wn * 64 + nf * 16 + lr;
        int cc = (ks * 4 + lk) ^ (row & 7);
        b[nf] = *(const short8*)&Bs[row * 64 + cc * 8];
      }
#pragma unroll
      for (int mf = 0; mf < 4; ++mf)
#pragma unroll
        for (int nf = 0; nf < 4; ++nf)
          acc[mf][nf] = MFMA16(a[mf], b[nf], acc[mf][nf]);
    }
  }

#pragma unroll
  for (int mf = 0; mf < 4; ++mf) {
#pragma unroll
    for (int nf = 0; nf < 4; ++nf) {
      int col = nBase + wn * 64 + nf * 16 + lr;
      float bv = bias ? bias[col] : 0.f;
#pragma unroll
      for (int i = 0; i < 4; ++i) {
        int row = mBase + wm * 64 + mf * 16 + lk * 4 + i;
        C[(size_t)row * N + col] = acc[mf][nf][i] + bv;
      }
    }
  }
}

// ---- persistent recurrence kernel -----------------------------------------
// 192 WGs x 256 thr, plain launch, all co-resident (1 WG/CU).
// Blocks 0..63: layer0 (16 units). Blocks 64..191: layer1 (8 units).
// arr0[4]: each +16 per layer0 iter. arr1[8]: each +16 per layer1 iter.
// Layer0 iter i (0..127): wait arr0>=16*i, read h0[i], write h0[i+1].
// Layer1 iter i (1..128): wait arr0>=16*i & arr1>=16*(i-1); computes t=i-1.

struct PParams {
  const float* zx0;             // [128][32][4096]
  const unsigned short* whh0;   // [4096][1024] bf16
  const unsigned short* wih1;   // [4096][1024] bf16
  const unsigned short* whh1;   // [4096][1024] bf16
  const float* bsum1;           // [4096]
  const float* cell;            // [2][32][1024] f32
  unsigned short* h0hist;       // [129][32][1024] bf16
  const unsigned short* h1init; // [32][1024] bf16
  unsigned short* outb;         // [32][128][1024] bf16
  unsigned int* arr0;           // 4 counters, 1KB apart (pre-zeroed)
  unsigned int* arr1;           // 8 counters, 1KB apart (pre-zeroed)
};

__global__ __launch_bounds__(256, 1) void lstm_persist_k(PParams P) {
  const int tid = threadIdx.x;
  const int lane = tid & 63;
  const int w = tid >> 6;
  const int lr = lane & 15, lkk = lane >> 4;

  __shared__ float zbuf[32][68];

  if (blockIdx.x < 64) {
    // ---------------- layer 0: units u0..u0+15 ----------------
    const int u0 = blockIdx.x * 16;
    const int grp = blockIdx.x & 3;
    const int m = w >> 1;
    const int p = w & 1;
    const int g0 = p * 2, g1 = p * 2 + 1;

    short8 bw0[32], bw1[32];
    {
      const unsigned short* r0 = P.whh0 + (size_t)(g0 * 1024 + u0 + lr) * 1024 + lkk * 8;
      const unsigned short* r1 = P.whh0 + (size_t)(g1 * 1024 + u0 + lr) * 1024 + lkk * 8;
#pragma unroll
      for (int ks = 0; ks < 32; ++ks) {
        bw0[ks] = *(const short8*)(r0 + ks * 32);
        bw1[ks] = *(const short8*)(r1 + ks * 32);
      }
    }
    // fusion: thread -> (batch fb, unit pair u0+2*jp, u0+2*jp+1)
    const int fb = tid >> 3;          // 0..31
    const int jp = tid & 7;           // 0..7
    float creg[2];
    creg[0] = P.cell[fb * 1024 + u0 + 2 * jp];
    creg[1] = P.cell[fb * 1024 + u0 + 2 * jp + 1];

    for (int i = 0; i < 128; ++i) {
      if (i > 0 && tid < 4) poll_ge(&P.arr0[tid * 256], (unsigned)(16 * i));
      asm volatile("" ::: "memory");
      __syncthreads();

      // zx0 prefetch (plain loads; latency hides under MFMA block)
      float2 zr[4];
      {
        const float2* br = (const float2*)(P.zx0 + (size_t)i * 131072 + fb * 4096 + u0 + 2 * jp);
#pragma unroll
        for (int g = 0; g < 4; ++g) zr[g] = br[g * 512];
      }
      f32x4 acc0 = {0.f, 0.f, 0.f, 0.f}, acc1 = {0.f, 0.f, 0.f, 0.f};
      const unsigned short* ap =
          P.h0hist + (size_t)i * 32768 + (size_t)(m * 16 + lr) * 1024 + lkk * 8;
#pragma unroll
      for (int g4 = 0; g4 < 4; ++g4) {
        short8 a[8];
#pragma unroll
        for (int q = 0; q < 8; ++q) a[q] = ld16_dev(ap + (g4 * 8 + q) * 32);
#pragma unroll
        for (int q = 0; q < 8; ++q) {
          acc0 = MFMA16(a[q], bw0[g4 * 8 + q], acc0);
          acc1 = MFMA16(a[q], bw1[g4 * 8 + q], acc1);
        }
      }
#pragma unroll
      for (int j = 0; j < 4; ++j) {
        zbuf[m * 16 + lkk * 4 + j][g0 * 16 + lr] = acc0[j];
        zbuf[m * 16 + lkk * 4 + j][g1 * 16 + lr] = acc1[j];
      }
      __syncthreads();

      unsigned hv = 0;
#pragma unroll
      for (int u = 0; u < 2; ++u) {
        int j = 2 * jp + u;
        float zi = zbuf[fb][j]      + ((u == 0) ? zr[0].x : zr[0].y);
        float zf = zbuf[fb][16 + j] + ((u == 0) ? zr[1].x : zr[1].y);
        float zg = zbuf[fb][32 + j] + ((u == 0) ? zr[2].x : zr[2].y);
        float zo = zbuf[fb][48 + j] + ((u == 0) ? zr[3].x : zr[3].y);
        float ii = 1.f / (1.f + __expf(-zi));
        float ff = 1.f / (1.f + __expf(-zf));
        float gg = tanhf(zg);
        float oo = 1.f / (1.f + __expf(-zo));
        float cn = ff * creg[u] + ii * gg;
        creg[u] = cn;
        float hn = oo * tanhf(cn);
        hv |= ((unsigned)f2bf(hn)) << (16 * u);
      }
      st_u32_dev((unsigned*)&P.h0hist[(size_t)(i + 1) * 32768 + fb * 1024 + u0 + 2 * jp], hv);

      __syncthreads();   // per-wave vmcnt(0) drain => h stores at coherence pt
      if (tid == 0) arrive(&P.arr0[grp * 256]);
    }
  } else {
    // ---------------- layer 1: units u0..u0+7 ----------------
    const int u0 = (blockIdx.x - 64) * 8;
    const int grp = (blockIdx.x - 64) & 7;
    const int m = w >> 1;
    const int n = w & 1;
    const int gA = (n * 16 + lr) >> 3;
    const int un = (n * 16 + lr) & 7;
    const size_t R = (size_t)(gA * 1024 + u0 + un) * 1024;

    short8 bwi[32], bwh[32];
#pragma unroll
    for (int ks = 0; ks < 32; ++ks) {
      bwi[ks] = *(const short8*)(P.wih1 + R + ks * 32 + lkk * 8);
      bwh[ks] = *(const short8*)(P.whh1 + R + ks * 32 + lkk * 8);
    }
    // fusion: threads 0..127 -> (batch fb, unit pair 2*jp, 2*jp+1)
    const int fb = tid >> 2;          // 0..63 (only <32 used via tid<128)
    const int jp = tid & 3;           // 0..3
    float creg[2] = {0.f, 0.f};
    float brg[4][2];
    if (tid < 128) {
      creg[0] = P.cell[32768 + fb * 1024 + u0 + 2 * jp];
      creg[1] = P.cell[32768 + fb * 1024 + u0 + 2 * jp + 1];
#pragma unroll
      for (int g = 0; g < 4; ++g) {
        brg[g][0] = P.bsum1[g * 1024 + u0 + 2 * jp];
        brg[g][1] = P.bsum1[g * 1024 + u0 + 2 * jp + 1];
      }
    }

    for (int i = 1; i <= 128; ++i) {
      if (tid < 12) {
        if (tid < 4) poll_ge(&P.arr0[tid * 256], (unsigned)(16 * i));
        else if (i > 1) poll_ge(&P.arr1[(tid - 4) * 256], (unsigned)(16 * (i - 1)));
      }
      asm volatile("" ::: "memory");
      __syncthreads();

      f32x4 accA = {0.f, 0.f, 0.f, 0.f}, accB = {0.f, 0.f, 0.f, 0.f};
      const unsigned short* a0p =
          P.h0hist + (size_t)i * 32768 + (size_t)(m * 16 + lr) * 1024 + lkk * 8;
      size_t h1s = (i == 1) ? 1024 : 131072;
      const unsigned short* h1b =
          (i == 1) ? P.h1init : (P.outb + (size_t)(i - 2) * 1024);
      const unsigned short* a1p = h1b + (size_t)(m * 16 + lr) * h1s + lkk * 8;
#pragma unroll
      for (int g4 = 0; g4 < 4; ++g4) {
        short8 a0[8], a1[8];
#pragma unroll
        for (int q = 0; q < 8; ++q) {
          a0[q] = ld16_dev(a0p + (g4 * 8 + q) * 32);
          a1[q] = ld16_dev(a1p + (g4 * 8 + q) * 32);
        }
#pragma unroll
        for (int q = 0; q < 8; ++q) {
          accA = MFMA16(a0[q], bwi[g4 * 8 + q], accA);
          accB = MFMA16(a1[q], bwh[g4 * 8 + q], accB);
        }
      }
      f32x4 acc = accA + accB;
#pragma unroll
      for (int j = 0; j < 4; ++j)
        zbuf[m * 16 + lkk * 4 + j][n * 16 + lr] = acc[j];
      __syncthreads();

      if (tid < 128) {
        unsigned hv = 0;
#pragma unroll
        for (int u = 0; u < 2; ++u) {
          int j = 2 * jp + u;
          float zi = zbuf[fb][j]      + brg[0][u];
          float zf = zbuf[fb][8 + j]  + brg[1][u];
          float zg = zbuf[fb][16 + j] + brg[2][u];
          float zo = zbuf[fb][24 + j] + brg[3][u];
          float ii = 1.f / (1.f + __expf(-zi));
          float ff = 1.f / (1.f + __expf(-zf));
          float gg = tanhf(zg);
          float oo = 1.f / (1.f + __expf(-zo));
          float cn = ff * creg[u] + ii * gg;
          creg[u] = cn;
          float hn = oo * tanhf(cn);
          hv |= ((unsigned)f2bf(hn)) << (16 * u);
        }
        st_u32_dev((unsigned*)&P.outb[(size_t)fb * 131072 + (size_t)(i - 1) * 1024 + u0 + 2 * jp], hv);
      }

      __syncthreads();   // drain outb stores
      if (tid == 0) arrive(&P.arr1[grp * 256]);
    }
  }
}

// ---------------------------------------------------------------------------

extern "C" void kernel_launch(void* const* d_in, const int* in_sizes, int n_in,
                              void* d_out, int out_size, void* d_ws, size_t ws_size,
                              hipStream_t stream) {
  const int*   x      = (const int*)d_in[0];
  const float* hidden = (const float*)d_in[1];
  const float* cell   = (const float*)d_in[2];
  const int*   target = (const int*)d_in[3];
  const float* emb    = (const float*)d_in[5];
  const float* w_ih   = (const float*)d_in[6];
  const float* w_hh   = (const float*)d_in[7];
  const float* b_ih   = (const float*)d_in[8];
  const float* b_hh   = (const float*)d_in[9];
  float* out = (float*)d_out;
  char* ws = (char*)d_ws;

  // ws layout (bytes)
  unsigned short* emb_bf  = (unsigned short*)(ws);                 // 65,536,000
  unsigned short* wih0_bf = (unsigned short*)(ws + 65536000);      //  8,388,608
  unsigned short* whh_bf  = (unsigned short*)(ws + 73924608);      // 16,777,216 (both layers)
  unsigned short* wih1_bf = (unsigned short*)(ws + 90701824);      //  8,388,608
  float*          bsum    = (float*)(ws + 99090432);               //     32,768
  unsigned short* outb    = (unsigned short*)(ws + 99123200);      //  8,388,608
  unsigned int*   barmem  = (unsigned int*)(ws + 107511808);       //     16,384
  // Large transients in d_out's dead space (proj GEMM overwrites last):
  float*          zx0    = (float*)((char*)d_out);                         // 67,108,864
  unsigned short* xseq   = (unsigned short*)((char*)d_out + 67108864);     //  8,388,608
  unsigned short* h0hist = (unsigned short*)((char*)d_out + 75497472);     //  8,454,144
  unsigned short* h1init = (unsigned short*)((char*)d_out + 83951616);     //     65,536

  hipMemsetAsync(barmem, 0, 16384, stream);
  cvt_bf16_k<<<2048, 256, 0, stream>>>(emb, emb_bf, 8192000);
  cvt_bf16_k<<<1024, 256, 0, stream>>>(w_ih, wih0_bf, 1048576);
  cvt_bf16_k<<<2048, 256, 0, stream>>>(w_hh, whh_bf, 2097152);
  cvt_bf16_k<<<1024, 256, 0, stream>>>(w_ih + 4194304, wih1_bf, 1048576);
  cvt_bf16_k<<<32, 256, 0, stream>>>(hidden, h0hist, 8192);          // h0hist[0]
  cvt_bf16_k<<<32, 256, 0, stream>>>(hidden + 32768, h1init, 8192);
  bias_sum_k<<<32, 256, 0, stream>>>(b_ih, b_hh, bsum, 8192);
  embed_k<<<4096, 256, 0, stream>>>(x, target, emb, xseq);

  // Zx0 = x_seq @ w_ih[0]^T + bsum0   [4096 x 4096]
  gemm_bf16_k<<<dim3(32, 32), 256, 0, stream>>>(xseq, wih0_bf, zx0, bsum, 4096);

  // persistent recurrence: 192 WGs, fence-free producer/consumer counters
  PParams pp;
  pp.zx0 = zx0;
  pp.whh0 = whh_bf;
  pp.wih1 = wih1_bf;
  pp.whh1 = whh_bf + 4194304;
  pp.bsum1 = bsum + 4096;
  pp.cell = cell;
  pp.h0hist = h0hist;
  pp.h1init = h1init;
  pp.outb = outb;
  pp.arr0 = barmem;                // 4 counters, 1KB apart
  pp.arr1 = barmem + 4 * 256;      // 8 counters, 1KB apart
  lstm_persist_k<<<192, 256, 0, stream>>>(pp);

  // out = outb @ emb_bf^T   [4096 x 32000]
  gemm_bf16_k<<<dim3(250, 32), 256, 0, stream>>>(outb, emb_bf, out, nullptr, 32000);
}

// Round 6
// 4097.329 us; speedup vs baseline: 1.1011x; 1.1011x over previous
//
#include <hip/hip_runtime.h>
#include <stdint.h>

// ---------------------------------------------------------------------------
// DecoderLSTM: B=32, S=128, H=1024, L=2, V=32000, teacher forcing (tf=1)
//
//   1. cvt weights/emb -> bf16, bsum = b_ih+b_hh, h/c inits.
//   2. embed tokens -> x_seq bf16 [4096][1024] (rows t*32+b)     (in d_out)
//   3. Zx0 = x_seq @ w_ih[0]^T + bsum0  (MFMA GEMM, f32)         (in d_out)
//   4. ONE persistent kernel, fence-free producer/consumer sync.
//      WEIGHTS LIVE IN LDS (128 KB/WG), pre-arranged fragment-major so each
//      MFMA B-operand is one conflict-free ds_read_b128. (Round 3-5 kept
//      them in "registers" -> 256 VGPR arrays spilled to scratch ->
//      latency-bound reload chain was the 20 us/iter floor.)
//   5. out = outb @ emb_bf^T (MFMA GEMM, M=4096, N=32000, K=1024)
// ---------------------------------------------------------------------------

typedef __attribute__((ext_vector_type(8))) short short8;
typedef __attribute__((ext_vector_type(4))) float f32x4;

#define MFMA16(a, b, c) __builtin_amdgcn_mfma_f32_16x16x32_bf16((a), (b), (c), 0, 0, 0)

__device__ __forceinline__ unsigned short f2bf(float f) {
  union { float f; unsigned int u; } v; v.f = f;
  unsigned int u = v.u;
  return (unsigned short)((u + 0x7fffu + ((u >> 16) & 1u)) >> 16);
}

// device-coherent (sc1) primitives: relaxed AGENT atomics.
__device__ __forceinline__ void st_u32_dev(unsigned* p, unsigned v) {
  __hip_atomic_store(p, v, __ATOMIC_RELAXED, __HIP_MEMORY_SCOPE_AGENT);
}
__device__ __forceinline__ short8 ld16_dev(const unsigned short* p) {
  union { unsigned long long q[2]; short8 v; } r;
  const unsigned long long* pp = (const unsigned long long*)p;
  r.q[0] = __hip_atomic_load(pp, __ATOMIC_RELAXED, __HIP_MEMORY_SCOPE_AGENT);
  r.q[1] = __hip_atomic_load(pp + 1, __ATOMIC_RELAXED, __HIP_MEMORY_SCOPE_AGENT);
  return r.v;
}
__device__ __forceinline__ void poll_ge(unsigned* c, unsigned tgt) {
  while (__hip_atomic_load(c, __ATOMIC_RELAXED, __HIP_MEMORY_SCOPE_AGENT) < tgt)
    __builtin_amdgcn_s_sleep(1);
}
__device__ __forceinline__ void arrive(unsigned* c) {
  __hip_atomic_fetch_add(c, 1u, __ATOMIC_RELAXED, __HIP_MEMORY_SCOPE_AGENT);
}

// ---- conversion / small kernels -------------------------------------------

__global__ void cvt_bf16_k(const float* __restrict__ s, unsigned short* __restrict__ d, int n4) {
  int i = blockIdx.x * blockDim.x + threadIdx.x;
  int st = gridDim.x * blockDim.x;
  for (; i < n4; i += st) {
    float4 v = ((const float4*)s)[i];
    ushort4 o;
    o.x = f2bf(v.x); o.y = f2bf(v.y); o.z = f2bf(v.z); o.w = f2bf(v.w);
    ((ushort4*)d)[i] = o;
  }
}

__global__ void bias_sum_k(const float* __restrict__ a, const float* __restrict__ b,
                           float* __restrict__ o, int n) {
  int i = blockIdx.x * blockDim.x + threadIdx.x;
  if (i < n) o[i] = a[i] + b[i];
}

__global__ void embed_k(const int* __restrict__ x, const int* __restrict__ tgt,
                        const float* __restrict__ emb, unsigned short* __restrict__ xseq) {
  int row = blockIdx.x;          // t*32 + b
  int t = row >> 5, b = row & 31;
  int tok = (t == 0) ? x[b] : tgt[b * 128 + t];
  const float4* e = (const float4*)(emb + (size_t)tok * 1024);
  ushort4* o = (ushort4*)(xseq + (size_t)row * 1024);
  int i = threadIdx.x;
  float4 v = e[i];
  ushort4 u;
  u.x = f2bf(v.x); u.y = f2bf(v.y); u.z = f2bf(v.z); u.w = f2bf(v.w);
  o[i] = u;
}

// ---- bf16 MFMA GEMM: C[M][N] = A[M][K] * B[N][K]^T (+bias[col]) -----------
// (verified in round 1; unchanged)

__global__ __launch_bounds__(256, 2) void gemm_bf16_k(
    const unsigned short* __restrict__ A, const unsigned short* __restrict__ B,
    float* __restrict__ C, const float* __restrict__ bias, int N) {
  __shared__ __align__(16) unsigned short As[128 * 64];
  __shared__ __align__(16) unsigned short Bs[128 * 64];
  const int tid = threadIdx.x;
  const int lane = tid & 63;
  const int w = tid >> 6;
  const int wm = w >> 1, wn = w & 1;
  const int mBase = blockIdx.y * 128;
  const int nBase = blockIdx.x * 128;
  const int lr = lane & 15, lk = lane >> 4;
  const int K = 1024;

  f32x4 acc[4][4];
#pragma unroll
  for (int i = 0; i < 4; ++i)
#pragma unroll
    for (int j = 0; j < 4; ++j) acc[i][j] = (f32x4){0.f, 0.f, 0.f, 0.f};

  for (int kt = 0; kt < K / 64; ++kt) {
    int4 va[4], vb[4];
#pragma unroll
    for (int r = 0; r < 4; ++r) {
      int q = r * 256 + tid;
      int row = q >> 3, c = q & 7;
      va[r] = *(const int4*)(A + (size_t)(mBase + row) * K + kt * 64 + c * 8);
      vb[r] = *(const int4*)(B + (size_t)(nBase + row) * K + kt * 64 + c * 8);
    }
    __syncthreads();
#pragma unroll
    for (int r = 0; r < 4; ++r) {
      int q = r * 256 + tid;
      int row = q >> 3, c = q & 7;
      int cs = c ^ (row & 7);
      *(int4*)&As[row * 64 + cs * 8] = va[r];
      *(int4*)&Bs[row * 64 + cs * 8] = vb[r];
    }
    __syncthreads();
#pragma unroll
    for (int ks = 0; ks < 2; ++ks) {
      short8 a[4], b[4];
#pragma unroll
      for (int mf = 0; mf < 4; ++mf) {
        int row = wm * 64 + mf * 16 + lr;
        int cc = (ks * 4 + lk) ^ (row & 7);
        a[mf] = *(const short8*)&As[row * 64 + cc * 8];
      }
#pragma unroll
      for (int nf = 0; nf < 4; ++nf) {
        int row = wn * 64 + nf * 16 + lr;
        int cc = (ks * 4 + lk) ^ (row & 7);
        b[nf] = *(const short8*)&Bs[row * 64 + cc * 8];
      }
#pragma unroll
      for (int mf = 0; mf < 4; ++mf)
#pragma unroll
        for (int nf = 0; nf < 4; ++nf)
          acc[mf][nf] = MFMA16(a[mf], b[nf], acc[mf][nf]);
    }
  }

#pragma unroll
  for (int mf = 0; mf < 4; ++mf) {
#pragma unroll
    for (int nf = 0; nf < 4; ++nf) {
      int col = nBase + wn * 64 + nf * 16 + lr;
      float bv = bias ? bias[col] : 0.f;
#pragma unroll
      for (int i = 0; i < 4; ++i) {
        int row = mBase + wm * 64 + mf * 16 + lk * 4 + i;
        C[(size_t)row * N + col] = acc[mf][nf][i] + bv;
      }
    }
  }
}

// ---- persistent recurrence kernel -----------------------------------------
// 192 WGs x 256 thr, plain launch, all co-resident (1 WG/CU, LDS-bound).
// Blocks 0..63: layer0 (16 units). Blocks 64..191: layer1 (8 units).
// Weights in LDS as 128 fragments of 1KB: frag f, lane l at wlds[f*512+l*8],
// element (l, j) = W[tile_row(f, l&15)][kc(f)*32 + (l>>4)*8 + j].
// ds_read_b128 per fragment: lane l reads 16B at l*16 -> conflict-free.

struct PParams {
  const float* zx0;             // [128][32][4096]
  const unsigned short* whh0;   // [4096][1024] bf16
  const unsigned short* wih1;   // [4096][1024] bf16
  const unsigned short* whh1;   // [4096][1024] bf16
  const float* bsum1;           // [4096]
  const float* cell;            // [2][32][1024] f32
  unsigned short* h0hist;       // [129][32][1024] bf16
  const unsigned short* h1init; // [32][1024] bf16
  unsigned short* outb;         // [32][128][1024] bf16
  unsigned int* arr0;           // 4 counters, 1KB apart (pre-zeroed)
  unsigned int* arr1;           // 8 counters, 1KB apart (pre-zeroed)
};

__global__ __launch_bounds__(256, 1) void lstm_persist_k(PParams P) {
  const int tid = threadIdx.x;
  const int lane = tid & 63;
  const int w = tid >> 6;
  const int lr = lane & 15, lkk = lane >> 4;

  __shared__ __align__(16) unsigned short wlds[65536];   // 128 KB weight frags
  __shared__ float zbuf[32][68];

  if (blockIdx.x < 64) {
    // ---------------- layer 0: units u0..u0+15 ----------------
    const int u0 = blockIdx.x * 16;
    const int grp = blockIdx.x & 3;
    const int m = w >> 1;
    const int p = w & 1;
    const int g0 = p * 2, g1 = p * 2 + 1;

    // fill LDS frags: f = g*32 + kc  (g = gate tile 0..3, kc = k-chunk 0..31)
    for (int f = w; f < 128; f += 4) {
      int g = f >> 5, kc = f & 31;
      const unsigned short* src =
          P.whh0 + (size_t)(g * 1024 + u0 + lr) * 1024 + kc * 32 + lkk * 8;
      *(short8*)&wlds[f * 512 + lane * 8] = *(const short8*)src;
    }
    // fusion: thread -> (batch fb, unit pair u0+2*jp, u0+2*jp+1)
    const int fb = tid >> 3;          // 0..31
    const int jp = tid & 7;           // 0..7
    float creg[2];
    creg[0] = P.cell[fb * 1024 + u0 + 2 * jp];
    creg[1] = P.cell[fb * 1024 + u0 + 2 * jp + 1];
    __syncthreads();

    for (int i = 0; i < 128; ++i) {
      if (i > 0 && tid < 4) poll_ge(&P.arr0[tid * 256], (unsigned)(16 * i));
      asm volatile("" ::: "memory");
      __syncthreads();

      // zx0 prefetch (latency hides under MFMA block)
      float2 zr[4];
      {
        const float2* br = (const float2*)(P.zx0 + (size_t)i * 131072 + fb * 4096 + u0 + 2 * jp);
#pragma unroll
        for (int g = 0; g < 4; ++g) zr[g] = br[g * 512];
      }
      f32x4 acc0 = {0.f, 0.f, 0.f, 0.f}, acc1 = {0.f, 0.f, 0.f, 0.f};
      const unsigned short* ap =
          P.h0hist + (size_t)i * 32768 + (size_t)(m * 16 + lr) * 1024 + lkk * 8;
#pragma unroll
      for (int g4 = 0; g4 < 4; ++g4) {
        short8 a[8];
#pragma unroll
        for (int q = 0; q < 8; ++q) a[q] = ld16_dev(ap + (g4 * 8 + q) * 32);
#pragma unroll
        for (int q = 0; q < 8; ++q) {
          int kc = g4 * 8 + q;
          short8 b0 = *(const short8*)&wlds[(g0 * 32 + kc) * 512 + lane * 8];
          short8 b1 = *(const short8*)&wlds[(g1 * 32 + kc) * 512 + lane * 8];
          acc0 = MFMA16(a[q], b0, acc0);
          acc1 = MFMA16(a[q], b1, acc1);
        }
      }
#pragma unroll
      for (int j = 0; j < 4; ++j) {
        zbuf[m * 16 + lkk * 4 + j][g0 * 16 + lr] = acc0[j];
        zbuf[m * 16 + lkk * 4 + j][g1 * 16 + lr] = acc1[j];
      }
      __syncthreads();

      unsigned hv = 0;
#pragma unroll
      for (int u = 0; u < 2; ++u) {
        int j = 2 * jp + u;
        float zi = zbuf[fb][j]      + ((u == 0) ? zr[0].x : zr[0].y);
        float zf = zbuf[fb][16 + j] + ((u == 0) ? zr[1].x : zr[1].y);
        float zg = zbuf[fb][32 + j] + ((u == 0) ? zr[2].x : zr[2].y);
        float zo = zbuf[fb][48 + j] + ((u == 0) ? zr[3].x : zr[3].y);
        float ii = 1.f / (1.f + __expf(-zi));
        float ff = 1.f / (1.f + __expf(-zf));
        float gg = tanhf(zg);
        float oo = 1.f / (1.f + __expf(-zo));
        float cn = ff * creg[u] + ii * gg;
        creg[u] = cn;
        float hn = oo * tanhf(cn);
        hv |= ((unsigned)f2bf(hn)) << (16 * u);
      }
      st_u32_dev((unsigned*)&P.h0hist[(size_t)(i + 1) * 32768 + fb * 1024 + u0 + 2 * jp], hv);

      __syncthreads();   // per-wave vmcnt(0) drain => h stores at coherence pt
      if (tid == 0) arrive(&P.arr0[grp * 256]);
    }
  } else {
    // ---------------- layer 1: units u0..u0+7 ----------------
    const int u0 = (blockIdx.x - 64) * 8;
    const int grp = (blockIdx.x - 64) & 7;
    const int m = w >> 1;
    const int n = w & 1;

    // fill LDS frags: f = mat*64 + nt*32 + kc (mat 0=wih1,1=whh1; nt=0..1)
    for (int f = w; f < 128; f += 4) {
      int mat = f >> 6, nt = (f >> 5) & 1, kc = f & 31;
      int rr = nt * 16 + lr;
      int gate = rr >> 3, unit = rr & 7;
      const unsigned short* Wm = mat ? P.whh1 : P.wih1;
      const unsigned short* src =
          Wm + (size_t)(gate * 1024 + u0 + unit) * 1024 + kc * 32 + lkk * 8;
      *(short8*)&wlds[f * 512 + lane * 8] = *(const short8*)src;
    }
    // fusion: threads 0..127 -> (batch fb, unit pair 2*jp, 2*jp+1)
    const int fb = tid >> 2;          // 0..63 (only <32 used via tid<128)
    const int jp = tid & 3;           // 0..3
    float creg[2] = {0.f, 0.f};
    float brg[4][2];
    if (tid < 128) {
      creg[0] = P.cell[32768 + fb * 1024 + u0 + 2 * jp];
      creg[1] = P.cell[32768 + fb * 1024 + u0 + 2 * jp + 1];
#pragma unroll
      for (int g = 0; g < 4; ++g) {
        brg[g][0] = P.bsum1[g * 1024 + u0 + 2 * jp];
        brg[g][1] = P.bsum1[g * 1024 + u0 + 2 * jp + 1];
      }
    }
    __syncthreads();

    for (int i = 1; i <= 128; ++i) {
      if (tid < 12) {
        if (tid < 4) poll_ge(&P.arr0[tid * 256], (unsigned)(16 * i));
        else if (i > 1) poll_ge(&P.arr1[(tid - 4) * 256], (unsigned)(16 * (i - 1)));
      }
      asm volatile("" ::: "memory");
      __syncthreads();

      f32x4 accA = {0.f, 0.f, 0.f, 0.f}, accB = {0.f, 0.f, 0.f, 0.f};
      const unsigned short* a0p =
          P.h0hist + (size_t)i * 32768 + (size_t)(m * 16 + lr) * 1024 + lkk * 8;
      size_t h1s = (i == 1) ? 1024 : 131072;
      const unsigned short* h1b =
          (i == 1) ? P.h1init : (P.outb + (size_t)(i - 2) * 1024);
      const unsigned short* a1p = h1b + (size_t)(m * 16 + lr) * h1s + lkk * 8;
#pragma unroll
      for (int g4 = 0; g4 < 4; ++g4) {
        short8 a0[8], a1[8];
#pragma unroll
        for (int q = 0; q < 8; ++q) {
          a0[q] = ld16_dev(a0p + (g4 * 8 + q) * 32);
          a1[q] = ld16_dev(a1p + (g4 * 8 + q) * 32);
        }
#pragma unroll
        for (int q = 0; q < 8; ++q) {
          int kc = g4 * 8 + q;
          short8 bi = *(const short8*)&wlds[(n * 32 + kc) * 512 + lane * 8];
          short8 bh = *(const short8*)&wlds[(64 + n * 32 + kc) * 512 + lane * 8];
          accA = MFMA16(a0[q], bi, accA);
          accB = MFMA16(a1[q], bh, accB);
        }
      }
      f32x4 acc = accA + accB;
#pragma unroll
      for (int j = 0; j < 4; ++j)
        zbuf[m * 16 + lkk * 4 + j][n * 16 + lr] = acc[j];
      __syncthreads();

      if (tid < 128) {
        unsigned hv = 0;
#pragma unroll
        for (int u = 0; u < 2; ++u) {
          int j = 2 * jp + u;
          float zi = zbuf[fb][j]      + brg[0][u];
          float zf = zbuf[fb][8 + j]  + brg[1][u];
          float zg = zbuf[fb][16 + j] + brg[2][u];
          float zo = zbuf[fb][24 + j] + brg[3][u];
          float ii = 1.f / (1.f + __expf(-zi));
          float ff = 1.f / (1.f + __expf(-zf));
          float gg = tanhf(zg);
          float oo = 1.f / (1.f + __expf(-zo));
          float cn = ff * creg[u] + ii * gg;
          creg[u] = cn;
          float hn = oo * tanhf(cn);
          hv |= ((unsigned)f2bf(hn)) << (16 * u);
        }
        st_u32_dev((unsigned*)&P.outb[(size_t)fb * 131072 + (size_t)(i - 1) * 1024 + u0 + 2 * jp], hv);
      }

      __syncthreads();   // drain outb stores
      if (tid == 0) arrive(&P.arr1[grp * 256]);
    }
  }
}

// ---------------------------------------------------------------------------

extern "C" void kernel_launch(void* const* d_in, const int* in_sizes, int n_in,
                              void* d_out, int out_size, void* d_ws, size_t ws_size,
                              hipStream_t stream) {
  const int*   x      = (const int*)d_in[0];
  const float* hidden = (const float*)d_in[1];
  const float* cell   = (const float*)d_in[2];
  const int*   target = (const int*)d_in[3];
  const float* emb    = (const float*)d_in[5];
  const float* w_ih   = (const float*)d_in[6];
  const float* w_hh   = (const float*)d_in[7];
  const float* b_ih   = (const float*)d_in[8];
  const float* b_hh   = (const float*)d_in[9];
  float* out = (float*)d_out;
  char* ws = (char*)d_ws;

  // ws layout (bytes)
  unsigned short* emb_bf  = (unsigned short*)(ws);                 // 65,536,000
  unsigned short* wih0_bf = (unsigned short*)(ws + 65536000);      //  8,388,608
  unsigned short* whh_bf  = (unsigned short*)(ws + 73924608);      // 16,777,216 (both layers)
  unsigned short* wih1_bf = (unsigned short*)(ws + 90701824);      //  8,388,608
  float*          bsum    = (float*)(ws + 99090432);               //     32,768
  unsigned short* outb    = (unsigned short*)(ws + 99123200);      //  8,388,608
  unsigned int*   barmem  = (unsigned int*)(ws + 107511808);       //     16,384
  // Large transients in d_out's dead space (proj GEMM overwrites last):
  float*          zx0    = (float*)((char*)d_out);                         // 67,108,864
  unsigned short* xseq   = (unsigned short*)((char*)d_out + 67108864);     //  8,388,608
  unsigned short* h0hist = (unsigned short*)((char*)d_out + 75497472);     //  8,454,144
  unsigned short* h1init = (unsigned short*)((char*)d_out + 83951616);     //     65,536

  hipMemsetAsync(barmem, 0, 16384, stream);
  cvt_bf16_k<<<2048, 256, 0, stream>>>(emb, emb_bf, 8192000);
  cvt_bf16_k<<<1024, 256, 0, stream>>>(w_ih, wih0_bf, 1048576);
  cvt_bf16_k<<<2048, 256, 0, stream>>>(w_hh, whh_bf, 2097152);
  cvt_bf16_k<<<1024, 256, 0, stream>>>(w_ih + 4194304, wih1_bf, 1048576);
  cvt_bf16_k<<<32, 256, 0, stream>>>(hidden, h0hist, 8192);          // h0hist[0]
  cvt_bf16_k<<<32, 256, 0, stream>>>(hidden + 32768, h1init, 8192);
  bias_sum_k<<<32, 256, 0, stream>>>(b_ih, b_hh, bsum, 8192);
  embed_k<<<4096, 256, 0, stream>>>(x, target, emb, xseq);

  // Zx0 = x_seq @ w_ih[0]^T + bsum0   [4096 x 4096]
  gemm_bf16_k<<<dim3(32, 32), 256, 0, stream>>>(xseq, wih0_bf, zx0, bsum, 4096);

  // persistent recurrence: 192 WGs, fence-free producer/consumer counters
  PParams pp;
  pp.zx0 = zx0;
  pp.whh0 = whh_bf;
  pp.wih1 = wih1_bf;
  pp.whh1 = whh_bf + 4194304;
  pp.bsum1 = bsum + 4096;
  pp.cell = cell;
  pp.h0hist = h0hist;
  pp.h1init = h1init;
  pp.outb = outb;
  pp.arr0 = barmem;                // 4 counters, 1KB apart
  pp.arr1 = barmem + 4 * 256;      // 8 counters, 1KB apart
  lstm_persist_k<<<192, 256, 0, stream>>>(pp);

  // out = outb @ emb_bf^T   [4096 x 32000]
  gemm_bf16_k<<<dim3(250, 32), 256, 0, stream>>>(outb, emb_bf, out, nullptr, 32000);
}